// Round 8
// baseline (826.799 us; speedup 1.0000x reference)
//
#include <hip/hip_runtime.h>

#define NN 128
#define NITER 300
#define NROUND 4   // 4 rounds x 4-point bracket (/625) + 2 exact Newton steps.
                   // FIXED path (R4), no data-dependent exits; single-broadcast
                   // reductions (R6); f16-packed Q + dot2 (R7, absmax 2e-3 ok).

typedef __attribute__((ext_vector_type(2))) float v2f;
typedef _Float16 h2 __attribute__((ext_vector_type(2)));

#if __has_builtin(__builtin_amdgcn_fdot2)
  #define FDOT2(a, b, c) __builtin_amdgcn_fdot2((a), (b), (c), false)
#else
  #define FDOT2(a, b, c) fmaf((float)(a).x, (float)(b).x, \
                         fmaf((float)(a).y, (float)(b).y, (c)))
#endif

__device__ __forceinline__ int h2_to_i(h2 v) { union { h2 h; int i; } u; u.h = v; return u.i; }
__device__ __forceinline__ h2  i_to_h2(int x) { union { h2 h; int i; } u; u.i = x; return u.h; }

// ---- DPP wave-64 cross-lane helpers ----
template<int CTRL>
__device__ __forceinline__ float dpp0(float x) {  // invalid lanes contribute 0
  return __int_as_float(__builtin_amdgcn_update_dpp(0, __float_as_int(x), CTRL, 0xF, 0xF, true));
}
template<int CTRL>
__device__ __forceinline__ float dppS(float x) {  // invalid lanes keep self
  int xi = __float_as_int(x);
  return __int_as_float(__builtin_amdgcn_update_dpp(xi, xi, CTRL, 0xF, 0xF, false));
}
__device__ __forceinline__ float bcast63(float x) {
  return __int_as_float(__builtin_amdgcn_readlane(__float_as_int(x), 63));
}
__device__ __forceinline__ float rlane(float x, int l) {   // l literal after unroll
  return __int_as_float(__builtin_amdgcn_readlane(__float_as_int(x), l));
}
__device__ __forceinline__ int rlanei(int x, int l) {
  return __builtin_amdgcn_readlane(x, l);
}
__device__ __forceinline__ float wsum(float x) {
  x += dpp0<0x111>(x); x += dpp0<0x112>(x); x += dpp0<0x114>(x);
  x += dpp0<0x118>(x); x += dpp0<0x142>(x); x += dpp0<0x143>(x);
  return bcast63(x);
}
// 4 interleaved chains; cnt computed on lane63's totals, ONE bcast63 (R6)
__device__ __forceinline__ float wsum4_cnt(float a, float b, float c, float d) {
  a += dpp0<0x111>(a); b += dpp0<0x111>(b); c += dpp0<0x111>(c); d += dpp0<0x111>(d);
  a += dpp0<0x112>(a); b += dpp0<0x112>(b); c += dpp0<0x112>(c); d += dpp0<0x112>(d);
  a += dpp0<0x114>(a); b += dpp0<0x114>(b); c += dpp0<0x114>(c); d += dpp0<0x114>(d);
  a += dpp0<0x118>(a); b += dpp0<0x118>(b); c += dpp0<0x118>(c); d += dpp0<0x118>(d);
  a += dpp0<0x142>(a); b += dpp0<0x142>(b); c += dpp0<0x142>(c); d += dpp0<0x142>(d);
  a += dpp0<0x143>(a); b += dpp0<0x143>(b); c += dpp0<0x143>(c); d += dpp0<0x143>(d);
  float cnt = ((a > 1.f ? 1.f : 0.f) + (b > 1.f ? 1.f : 0.f))
            + ((c > 1.f ? 1.f : 0.f) + (d > 1.f ? 1.f : 0.f));
  return bcast63(cnt);
}
// 2 interleaved chains; tau computed on lane63's totals, ONE bcast63 (R6)
__device__ __forceinline__ float wsum2_tau(float sfv, float cnt) {
  float a = sfv, b = cnt;
  a += dpp0<0x111>(a); b += dpp0<0x111>(b);
  a += dpp0<0x112>(a); b += dpp0<0x112>(b);
  a += dpp0<0x114>(a); b += dpp0<0x114>(b);
  a += dpp0<0x118>(a); b += dpp0<0x118>(b);
  a += dpp0<0x142>(a); b += dpp0<0x142>(b);
  a += dpp0<0x143>(a); b += dpp0<0x143>(b);
  float nu    = floorf(b * (1.f / 1024.f));
  float nfree = fmaxf(b - 1024.f * nu, 1.f);
  float tau   = (a + nu - 1.f) * __builtin_amdgcn_rcpf(nfree);
  return bcast63(tau);
}
__device__ __forceinline__ void wminmax(float& mn, float& mx) {  // interleaved
  mn = fminf(mn, dppS<0x111>(mn)); mx = fmaxf(mx, dppS<0x111>(mx));
  mn = fminf(mn, dppS<0x112>(mn)); mx = fmaxf(mx, dppS<0x112>(mx));
  mn = fminf(mn, dppS<0x114>(mn)); mx = fmaxf(mx, dppS<0x114>(mx));
  mn = fminf(mn, dppS<0x118>(mn)); mx = fmaxf(mx, dppS<0x118>(mx));
  mn = fminf(mn, dppS<0x142>(mn)); mx = fmaxf(mx, dppS<0x142>(mx));
  mn = fminf(mn, dppS<0x143>(mn)); mx = fmaxf(mx, dppS<0x143>(mx));
  mn = bcast63(mn); mx = bcast63(mx);
}

// TWO WAVES PER SAMPLE (R8 = R2 structure + R7 f16 compression, no asm):
//   2048 waves -> 2 waves/SIMD (occupancy was pinned at 1 by the 1024-wave
//   grid in R0-R7, VALU ~30-40% stalled on serial DPP chains; the co-resident
//   wave now fills those bubbles).
//   Wave wid, lane l owns row r = 2l+wid: Q row f16-packed = 64 dwords.
//   Coord state (y for 2l, 2l+1) duplicated in both waves -> projection
//   duplicated (bit-identical, zero sync); only matvec outputs cross waves
//   (double-buffered LDS, ONE barrier/iter — R2-proven write(i+2)/read(i)
//   ordering). No AGPR shuttles: plain C, peak ~150 f32 regs in build.
__launch_bounds__(128, 2)
__global__ void markowitz_kernel(const float* __restrict__ rets,
                                 const float* __restrict__ cov,
                                 const float* __restrict__ gam,
                                 const float* __restrict__ alp,
                                 float* __restrict__ out)
{
  const int b    = blockIdx.x;
  const int tid  = threadIdx.x;
  const int wid  = tid >> 6;         // 0: even rows, 1: odd rows
  const int lane = tid & 63;

  __shared__ float pbuf[2][NN];      // matvec outputs, double-buffered
  __shared__ float fb[2];            // Frobenius half-sums

  const float g   = gam[b];
  const float g2  = g * g;
  const float aab = fabsf(alp[b]);
  const v2f* cb2 = (const v2f*)(cov + (size_t)b * (NN * NN));

  // ---------- build row r = 2*lane+wid of g2*C^T C + aab*I ----------
  v2f acc[64];                       // f32 accumulate, col pairs {2j, 2j+1}
  #pragma unroll
  for (int j = 0; j < 64; ++j) { v2f z = {0.f, 0.f}; acc[j] = z; }

  v2f c0 = cb2[lane];                // {C[0][2l], C[0][2l+1]}
  v2f c1 = cb2[64 + lane];
  #pragma unroll 2
  for (int k = 0; k < NN; ++k) {
    v2f c = c0; c0 = c1;
    const int kp = (k + 2 < NN) ? (k + 2) : (NN - 1);
    c1 = cb2[(size_t)kp * 64 + lane];
    const float aown = wid ? c.y : c.x;      // C[k][r]
    #pragma unroll
    for (int j = 0; j < 64; ++j) {
      float sx = rlane(c.x, j);              // C[k][2j]
      float sy = rlane(c.y, j);              // C[k][2j+1]
      acc[j].x = fmaf(aown, sx, acc[j].x);
      acc[j].y = fmaf(aown, sy, acc[j].y);
    }
  }

  // scale by g2, diagonal, Frobenius partial, f16 pack (acc dies into q)
  h2 q[64];
  float qd = 0.f;                    // f16-stored diagonal (f32) for y-quant fix
  const float dx = wid ? 0.f : aab;  // diag col r: pair j==lane, component wid
  const float dy = wid ? aab : 0.f;
  float s0 = 0.f, s1 = 0.f;
  #pragma unroll
  for (int j = 0; j < 64; ++j) {
    float qa = g2 * acc[j].x;
    float qb = g2 * acc[j].y;
    if (j == lane) { qa += dx; qb += dy; }
    s0 = fmaf(qa, qa, s0); s1 = fmaf(qb, qb, s1);
    h2 p; p.x = (_Float16)qa; p.y = (_Float16)qb;
    q[j] = p;
    if (j == lane) qd = wid ? (float)p.y : (float)p.x;
  }
  {
    float shalf = wsum(s0 + s1);
    if (lane == 0) fb[wid] = shalf;
  }
  __syncthreads();
  const float S    = fb[0] + fb[1];  // ||Q||_F^2 (f32, pre-rounding)
  const float step = 0.5f / sqrtf(S);
  const float sc   = 2.f * step;     // q is UNSCALED; scale applied post-exchange

  v2f rr = ((const v2f*)rets)[(size_t)b * 64 + lane];
  const float r2a = step * rr.x;
  const float r2b = step * rr.y;

  // ---------- FISTA ----------
  float y0 = 1.f / 128.f, y1 = 1.f / 128.f;   // coords (2l, 2l+1), duplicated
  float w0p = y0, w1p = y1;
  float t_f = 1.f;

  #pragma unroll 1
  for (int it = 0; it < NITER; ++it) {
    // momentum scalars hoisted (latency hides under matvec)
    float tn   = 0.5f * (1.f + sqrtf(1.f + 4.f * t_f * t_f));
    float coef = (t_f - 1.f) * __builtin_amdgcn_rcpf(tn);

    // pack y to f16 pair; residuals for diagonal correction
    h2 yp; yp.x = (_Float16)y0; yp.y = (_Float16)y1;
    const int ypi = h2_to_i(yp);
    float dy0 = y0 - (float)yp.x;
    float dy1 = y1 - (float)yp.y;
    float dyo = wid ? dy1 : dy0;               // residual of own coord r

    // matvec row r: 64 rlanei + 64 dot2, 4 interleaved chains
    float pa = 0.f, pb2 = 0.f, pc = 0.f, pd = 0.f;
    #pragma unroll
    for (int j = 0; j < 64; j += 4) {
      pa  = FDOT2(q[j],     i_to_h2(rlanei(ypi, j)),     pa);
      pb2 = FDOT2(q[j + 1], i_to_h2(rlanei(ypi, j + 1)), pb2);
      pc  = FDOT2(q[j + 2], i_to_h2(rlanei(ypi, j + 2)), pc);
      pd  = FDOT2(q[j + 3], i_to_h2(rlanei(ypi, j + 3)), pd);
    }
    float pr = ((pa + pb2) + (pc + pd)) + qd * dyo;   // (Q y)[r], y-quant fixed

    // exchange: dbuf -> ONE barrier per iteration (safe: write(i+2) of a
    // buffer happens after barrier(i+1), which implies read(i) completed)
    float* pbx = pbuf[it & 1];
    pbx[2 * lane + wid] = pr;
    __syncthreads();
    v2f pv = *(const v2f*)&pbuf[it & 1][2 * lane];
    float v0 = (y0 + r2a) - sc * pv.x;         // v = y - step*grad
    float v1 = (y1 + r2b) - sc * pv.y;

    // projection onto {sum w=1, 0<=w<=1}: 4 rounds x 4-point bracket search
    float mn = fminf(v0, v1), mx = fmaxf(v0, v1);
    wminmax(mn, mx);
    float lo = mn - 1.0f;
    float W  = mx - lo;
    #pragma unroll 1
    for (int r = 0; r < NROUND; ++r) {
      float h  = W * 0.2f;
      float t1v = lo + h, t2v = lo + 2.f*h, t3v = lo + 3.f*h, t4v = lo + 4.f*h;
      float sa = __builtin_amdgcn_fmed3f(v0 - t1v, 0.f, 1.f)
               + __builtin_amdgcn_fmed3f(v1 - t1v, 0.f, 1.f);
      float sb = __builtin_amdgcn_fmed3f(v0 - t2v, 0.f, 1.f)
               + __builtin_amdgcn_fmed3f(v1 - t2v, 0.f, 1.f);
      float sc4 = __builtin_amdgcn_fmed3f(v0 - t3v, 0.f, 1.f)
               + __builtin_amdgcn_fmed3f(v1 - t3v, 0.f, 1.f);
      float sd = __builtin_amdgcn_fmed3f(v0 - t4v, 0.f, 1.f)
               + __builtin_amdgcn_fmed3f(v1 - t4v, 0.f, 1.f);
      float cnt = wsum4_cnt(sa, sb, sc4, sd);  // ONE broadcast per round
      lo = fmaf(cnt, h, lo);
      W  = h;
    }
    float tauf = lo + 0.5f * W;

    // two exact active-set Newton steps; second also produces w
    float w0 = 0.f, w1 = 0.f;
    #pragma unroll
    for (int e = 0; e < 2; ++e) {
      float z0 = v0 - tauf, z1 = v1 - tauf;
      bool fr0 = (z0 > 0.f) && (z0 < 1.0f);
      bool fr1 = (z1 > 0.f) && (z1 < 1.0f);
      bool cp0 = (z0 >= 1.0f), cp1 = (z1 >= 1.0f);
      float sfv = (fr0 ? v0 : 0.f) + (fr1 ? v1 : 0.f);
      float cnt = (fr0 ? 1.f : 0.f) + (fr1 ? 1.f : 0.f)
                + 1024.f * ((cp0 ? 1.f : 0.f) + (cp1 ? 1.f : 0.f));
      tauf = wsum2_tau(sfv, cnt);              // ONE broadcast per step
      if (e == 1) {
        w0 = fr0 ? (v0 - tauf) : (cp0 ? 1.0f : 0.f);
        w1 = fr1 ? (v1 - tauf) : (cp1 ? 1.0f : 0.f);
      }
    }

    // FISTA momentum (identical in both waves -> states stay bit-identical)
    y0 = w0 + coef * (w0 - w0p);
    y1 = w1 + coef * (w1 - w1p);
    w0p = w0; w1p = w1;
    t_f = tn;
  }

  if (wid == 0) {
    v2f wv = { w0p, w1p };
    ((v2f*)out)[(size_t)b * 64 + lane] = wv;   // 8B coalesced store
  }
}

extern "C" void kernel_launch(void* const* d_in, const int* in_sizes, int n_in,
                              void* d_out, int out_size, void* d_ws, size_t ws_size,
                              hipStream_t stream) {
  (void)n_in; (void)d_ws; (void)ws_size; (void)out_size;
  const float* rets = (const float*)d_in[0];
  const float* cov  = (const float*)d_in[1];
  const float* gam  = (const float*)d_in[2];
  const float* alp  = (const float*)d_in[3];
  float* out = (float*)d_out;
  const int B = in_sizes[0] / NN;   // 1024 blocks x 2 waves = 2 waves/SIMD
  markowitz_kernel<<<B, 128, 0, stream>>>(rets, cov, gam, alp, out);
}